// Round 1
// baseline (2226.767 us; speedup 1.0000x reference)
//
#include <hip/hip_runtime.h>

#define DIM 128   // feature dim, fixed per reference
#define TM 64     // gemm tile rows
#define TN 64     // gemm tile cols

// ---------------- degree histogram ----------------
__global__ __launch_bounds__(256) void k_degrees(const int* __restrict__ src,
                                                 const int* __restrict__ dst,
                                                 int* __restrict__ deg_out,
                                                 int* __restrict__ deg_in, int E) {
    int e = blockIdx.x * 256 + threadIdx.x;
    if (e < E) {
        atomicAdd(&deg_out[src[e]], 1);
        atomicAdd(&deg_in[dst[e]], 1);
    }
}

// ---------------- norms = clamp(deg,1)^-0.5 ----------------
__global__ __launch_bounds__(256) void k_norms(const int* __restrict__ deg_out,
                                               const int* __restrict__ deg_in,
                                               float* __restrict__ norm_src,
                                               float* __restrict__ norm_dst, int N) {
    int i = blockIdx.x * 256 + threadIdx.x;
    if (i < N) {
        int dov = deg_out[i]; if (dov < 1) dov = 1;
        int div_ = deg_in[i]; if (div_ < 1) div_ = 1;
        norm_src[i] = rsqrtf((float)dov);
        norm_dst[i] = rsqrtf((float)div_);
    }
}

// ---------------- edge gather + atomic scatter-add ----------------
// 32 threads per edge, float4 per thread: coalesced 512B gather per edge row.
__global__ __launch_bounds__(256) void k_edge_agg(const float* __restrict__ h,
                                                  const int* __restrict__ src,
                                                  const int* __restrict__ dst,
                                                  const float* __restrict__ norm_src,
                                                  float* __restrict__ agg, int E) {
    int t = blockIdx.x * 256 + threadIdx.x;
    int e = t >> 5;
    int lane = t & 31;
    if (e >= E) return;
    int s = src[e];
    int d = dst[e];
    float ns = norm_src[s];
    float4 v = *((const float4*)(h + (size_t)s * DIM) + lane);
    float* o = agg + (size_t)d * DIM + lane * 4;
    atomicAdd(o + 0, v.x * ns);
    atomicAdd(o + 1, v.y * ns);
    atomicAdd(o + 2, v.z * ns);
    atomicAdd(o + 3, v.w * ns);
}

// ---------------- fused: out = relu((agg * norm_dst[:,None]) @ W + b) ----------------
// Block: 256 threads -> 64x64 output tile, 4x4 register blocking per thread.
// W staged k-major [128][64] in LDS (stride 64); A staged in 64-k chunks,
// stride 68 (+4 pad -> row step 272 % 32 == 16 -> 2-way bank aliasing, free).
__global__ __launch_bounds__(256) void k_gemm_norm_bias_relu(
        const float* __restrict__ A, const float* __restrict__ norm_dst,
        const float* __restrict__ W, const float* __restrict__ bias,
        float* __restrict__ out, int N) {
    __shared__ float As[TM * 68];      // 64 rows x 64 k-chunk, stride 68 (17408 B)
    __shared__ float Ws[DIM * TN];     // 128 k x 64 cols, stride 64   (32768 B)

    const int t = threadIdx.x;
    const int row0 = blockIdx.x * TM;
    const int c0 = blockIdx.y * TN;

    // stage W tile: 128x64 floats = 2048 float4, 8 per thread (coalesced)
    #pragma unroll
    for (int i = 0; i < 8; ++i) {
        int idx = (t + i * 256) * 4;     // float index in [128][64]
        int k = idx >> 6;
        int c = idx & 63;
        *(float4*)(Ws + idx) = *(const float4*)(W + (size_t)k * DIM + c0 + c);
    }

    const int tx = t & 15;   // col group: cols tx*4 .. tx*4+3
    const int ty = t >> 4;   // row group: rows ty*4 .. ty*4+3

    float acc[4][4];
    #pragma unroll
    for (int i = 0; i < 4; ++i)
        #pragma unroll
        for (int j = 0; j < 4; ++j) acc[i][j] = 0.f;

    for (int kt = 0; kt < DIM; kt += 64) {
        // stage A chunk: 64 rows x 64 k = 1024 float4, 4 per thread, scaled by norm_dst
        #pragma unroll
        for (int i = 0; i < 4; ++i) {
            int fidx = (t + i * 256) * 4;   // float index in [64][64]
            int r = fidx >> 6;
            int k = fidx & 63;
            int gr = row0 + r;
            float4 v = make_float4(0.f, 0.f, 0.f, 0.f);
            if (gr < N) {
                v = *(const float4*)(A + (size_t)gr * DIM + kt + k);
                float s = norm_dst[gr];
                v.x *= s; v.y *= s; v.z *= s; v.w *= s;
            }
            *(float4*)(As + r * 68 + k) = v;
        }
        __syncthreads();

        const float* Ab = As + ty * 4 * 68;
        const float* Wb = Ws + (size_t)kt * 64 + tx * 4;
        #pragma unroll
        for (int k = 0; k < 64; k += 4) {
            float a[4][4];   // [row][kk]
            float w[4][4];   // [kk][col]
            #pragma unroll
            for (int i = 0; i < 4; ++i)
                *(float4*)a[i] = *(const float4*)(Ab + i * 68 + k);
            #pragma unroll
            for (int kk = 0; kk < 4; ++kk)
                *(float4*)w[kk] = *(const float4*)(Wb + (k + kk) * 64);
            #pragma unroll
            for (int kk = 0; kk < 4; ++kk)
                #pragma unroll
                for (int i = 0; i < 4; ++i)
                    #pragma unroll
                    for (int j = 0; j < 4; ++j)
                        acc[i][j] += a[i][kk] * w[kk][j];
        }
        __syncthreads();
    }

    // epilogue: bias + relu, guarded float4 stores
    float bb[4];
    #pragma unroll
    for (int j = 0; j < 4; ++j) bb[j] = bias[c0 + tx * 4 + j];
    #pragma unroll
    for (int i = 0; i < 4; ++i) {
        int gr = row0 + ty * 4 + i;
        if (gr < N) {
            float4 o;
            o.x = fmaxf(acc[i][0] + bb[0], 0.f);
            o.y = fmaxf(acc[i][1] + bb[1], 0.f);
            o.z = fmaxf(acc[i][2] + bb[2], 0.f);
            o.w = fmaxf(acc[i][3] + bb[3], 0.f);
            *(float4*)(out + (size_t)gr * DIM + c0 + tx * 4) = o;
        }
    }
}

static inline size_t align_up(size_t x, size_t a) { return (x + a - 1) & ~(a - 1); }

extern "C" void kernel_launch(void* const* d_in, const int* in_sizes, int n_in,
                              void* d_out, int out_size, void* d_ws, size_t ws_size,
                              hipStream_t stream) {
    const float* features = (const float*)d_in[0];
    const int*   src      = (const int*)d_in[1];
    const int*   dst      = (const int*)d_in[2];
    const float* W1       = (const float*)d_in[3];
    const float* b1       = (const float*)d_in[4];
    const float* W2       = (const float*)d_in[5];
    const float* b2       = (const float*)d_in[6];
    float* out = (float*)d_out;

    const int N = in_sizes[0] / DIM;
    const int E = in_sizes[1];

    // workspace carve-up
    char* p = (char*)d_ws;
    int*   deg_out  = (int*)p;                 // [N]
    int*   deg_in   = (int*)(p + align_up((size_t)N * 4, 256));
    char*  p2 = p + 2 * align_up((size_t)N * 4, 256);
    float* norm_src = (float*)p2;
    float* norm_dst = (float*)(p2 + align_up((size_t)N * 4, 256));
    char*  p3 = p2 + 2 * align_up((size_t)N * 4, 256);
    float* agg = (float*)p3;                              // [N][128]
    float* h1  = (float*)(p3 + align_up((size_t)N * DIM * 4, 256));  // [N][128]

    const int edge_blocks   = (E + 255) / 256;
    const int node_blocks   = (N + 255) / 256;
    const int eagg_blocks   = (int)(((size_t)E * 32 + 255) / 256);
    dim3 gemm_grid((N + TM - 1) / TM, DIM / TN);

    // degrees + norms
    hipMemsetAsync(deg_out, 0, align_up((size_t)N * 4, 256) * 2, stream);
    k_degrees<<<edge_blocks, 256, 0, stream>>>(src, dst, deg_out, deg_in, E);
    k_norms<<<node_blocks, 256, 0, stream>>>(deg_out, deg_in, norm_src, norm_dst, N);

    // layer 1
    hipMemsetAsync(agg, 0, (size_t)N * DIM * 4, stream);
    k_edge_agg<<<eagg_blocks, 256, 0, stream>>>(features, src, dst, norm_src, agg, E);
    k_gemm_norm_bias_relu<<<gemm_grid, 256, 0, stream>>>(agg, norm_dst, W1, b1, h1, N);

    // layer 2
    hipMemsetAsync(agg, 0, (size_t)N * DIM * 4, stream);
    k_edge_agg<<<eagg_blocks, 256, 0, stream>>>(h1, src, dst, norm_src, agg, E);
    k_gemm_norm_bias_relu<<<gemm_grid, 256, 0, stream>>>(agg, norm_dst, W2, b2, out, N);
}

// Round 2
// 343.130 us; speedup vs baseline: 6.4896x; 6.4896x over previous
//
#include <hip/hip_runtime.h>

#define DIM 128   // feature dim, fixed per reference
#define TM 64     // gemm tile rows
#define TN 64     // gemm tile cols

// ---------------- degree histogram ----------------
__global__ __launch_bounds__(256) void k_degrees(const int* __restrict__ src,
                                                 const int* __restrict__ dst,
                                                 int* __restrict__ deg_out,
                                                 int* __restrict__ deg_in, int E) {
    int e = blockIdx.x * 256 + threadIdx.x;
    if (e < E) {
        atomicAdd(&deg_out[src[e]], 1);
        atomicAdd(&deg_in[dst[e]], 1);
    }
}

// ---------------- norms = clamp(deg,1)^-0.5 ----------------
__global__ __launch_bounds__(256) void k_norms(const int* __restrict__ deg_out,
                                               const int* __restrict__ deg_in,
                                               float* __restrict__ norm_src,
                                               float* __restrict__ norm_dst, int N) {
    int i = blockIdx.x * 256 + threadIdx.x;
    if (i < N) {
        int dov = deg_out[i]; if (dov < 1) dov = 1;
        int div_ = deg_in[i]; if (div_ < 1) div_ = 1;
        norm_src[i] = rsqrtf((float)dov);
        norm_dst[i] = rsqrtf((float)div_);
    }
}

// ---------------- scan step 1: per-block sums of deg_in ----------------
__global__ __launch_bounds__(256) void k_block_reduce(const int* __restrict__ deg,
                                                      int* __restrict__ bsum, int N) {
    __shared__ int wsum[4];
    int i = blockIdx.x * 256 + threadIdx.x;
    int x = (i < N) ? deg[i] : 0;
    // wave reduce
    #pragma unroll
    for (int off = 32; off > 0; off >>= 1) x += __shfl_down(x, off, 64);
    int lane = threadIdx.x & 63, wave = threadIdx.x >> 6;
    if (lane == 0) wsum[wave] = x;
    __syncthreads();
    if (threadIdx.x == 0) bsum[blockIdx.x] = wsum[0] + wsum[1] + wsum[2] + wsum[3];
}

// ---------------- scan step 2: exclusive scan of block sums (1 block) ----------------
__global__ __launch_bounds__(256) void k_scan_small(const int* __restrict__ bsum,
                                                    int* __restrict__ bpre, int B) {
    __shared__ int wsum[4];
    __shared__ int carry_s;
    if (threadIdx.x == 0) carry_s = 0;
    __syncthreads();
    int lane = threadIdx.x & 63, wave = threadIdx.x >> 6;
    for (int base = 0; base < B; base += 256) {
        int i = base + threadIdx.x;
        int x = (i < B) ? bsum[i] : 0;
        int orig = x;
        #pragma unroll
        for (int off = 1; off < 64; off <<= 1) {
            int y = __shfl_up(x, off, 64);
            if (lane >= off) x += y;
        }
        if (lane == 63) wsum[wave] = x;
        __syncthreads();
        if (threadIdx.x == 0) {
            int s = 0;
            for (int w = 0; w < 4; ++w) { int t = wsum[w]; wsum[w] = s; s += t; }
        }
        __syncthreads();
        x += wsum[wave] + carry_s;
        if (i < B) bpre[i] = x - orig;
        __syncthreads();
        if (threadIdx.x == 255) carry_s = x;
        __syncthreads();
    }
}

// ---------------- scan step 3: block-local scan + offset -> row_off ----------------
__global__ __launch_bounds__(256) void k_scan_final(const int* __restrict__ deg,
                                                    const int* __restrict__ bpre,
                                                    int* __restrict__ row_off, int N) {
    __shared__ int wsum[4];
    int i = blockIdx.x * 256 + threadIdx.x;
    int x = (i < N) ? deg[i] : 0;
    int orig = x;
    int lane = threadIdx.x & 63, wave = threadIdx.x >> 6;
    #pragma unroll
    for (int off = 1; off < 64; off <<= 1) {
        int y = __shfl_up(x, off, 64);
        if (lane >= off) x += y;
    }
    if (lane == 63) wsum[wave] = x;
    __syncthreads();
    if (threadIdx.x == 0) {
        int s = 0;
        for (int w = 0; w < 4; ++w) { int t = wsum[w]; wsum[w] = s; s += t; }
    }
    __syncthreads();
    x += wsum[wave] + bpre[blockIdx.x];
    if (i < N) row_off[i] = x - orig;   // exclusive prefix
    if (i == N - 1) row_off[N] = x;     // total
}

// ---------------- CSR fill: scatter src ids under dst buckets ----------------
__global__ __launch_bounds__(256) void k_csr_fill(const int* __restrict__ src,
                                                  const int* __restrict__ dst,
                                                  const int* __restrict__ row_off,
                                                  int* __restrict__ cursor,
                                                  int* __restrict__ csr_src, int E) {
    int e = blockIdx.x * 256 + threadIdx.x;
    if (e < E) {
        int d = dst[e];
        int pos = row_off[d] + atomicAdd(&cursor[d], 1);
        csr_src[pos] = src[e];
    }
}

// ---------------- prescale: out = in * norm_src[node] (float4 grid) ----------------
__global__ __launch_bounds__(256) void k_prescale(const float* __restrict__ in,
                                                  const float* __restrict__ norm,
                                                  float* __restrict__ out, int n4) {
    int i = blockIdx.x * 256 + threadIdx.x;
    if (i < n4) {
        float4 v = ((const float4*)in)[i];
        float s = norm[i >> 5];   // DIM/4 = 32 float4 per node
        v.x *= s; v.y *= s; v.z *= s; v.w *= s;
        ((float4*)out)[i] = v;
    }
}

// ---------------- CSR SpMM: agg[d] = norm_dst[d] * sum_{s in nbr(d)} hs[s] ----------------
// 32 lanes per node, float4 per lane; register accumulate, single write.
__global__ __launch_bounds__(256) void k_spmm(const float* __restrict__ hs,
                                              const int* __restrict__ csr_src,
                                              const int* __restrict__ row_off,
                                              const float* __restrict__ norm_dst,
                                              float* __restrict__ agg, int N) {
    int t = blockIdx.x * 256 + threadIdx.x;
    int node = t >> 5;
    int lane = t & 31;
    if (node >= N) return;
    int beg = row_off[node], end = row_off[node + 1];
    float4 acc = make_float4(0.f, 0.f, 0.f, 0.f);
    int i = beg;
    for (; i + 1 < end; i += 2) {   // 2-deep unroll for memory-level parallelism
        int s0 = csr_src[i];
        int s1 = csr_src[i + 1];
        float4 v0 = *((const float4*)(hs + (size_t)s0 * DIM) + lane);
        float4 v1 = *((const float4*)(hs + (size_t)s1 * DIM) + lane);
        acc.x += v0.x; acc.y += v0.y; acc.z += v0.z; acc.w += v0.w;
        acc.x += v1.x; acc.y += v1.y; acc.z += v1.z; acc.w += v1.w;
    }
    if (i < end) {
        int s0 = csr_src[i];
        float4 v0 = *((const float4*)(hs + (size_t)s0 * DIM) + lane);
        acc.x += v0.x; acc.y += v0.y; acc.z += v0.z; acc.w += v0.w;
    }
    float nd = norm_dst[node];
    acc.x *= nd; acc.y *= nd; acc.z *= nd; acc.w *= nd;
    *((float4*)(agg + (size_t)node * DIM) + lane) = acc;
}

// ---------------- fused: out = relu(agg @ W + b) ----------------
__global__ __launch_bounds__(256) void k_gemm_bias_relu(
        const float* __restrict__ A, const float* __restrict__ W,
        const float* __restrict__ bias, float* __restrict__ out, int N) {
    __shared__ float As[TM * 68];      // 64 rows x 64 k-chunk, stride 68
    __shared__ float Ws[DIM * TN];     // 128 k x 64 cols, stride 64

    const int t = threadIdx.x;
    const int row0 = blockIdx.x * TM;
    const int c0 = blockIdx.y * TN;

    #pragma unroll
    for (int i = 0; i < 8; ++i) {
        int idx = (t + i * 256) * 4;
        int k = idx >> 6;
        int c = idx & 63;
        *(float4*)(Ws + idx) = *(const float4*)(W + (size_t)k * DIM + c0 + c);
    }

    const int tx = t & 15;
    const int ty = t >> 4;

    float acc[4][4];
    #pragma unroll
    for (int i = 0; i < 4; ++i)
        #pragma unroll
        for (int j = 0; j < 4; ++j) acc[i][j] = 0.f;

    for (int kt = 0; kt < DIM; kt += 64) {
        #pragma unroll
        for (int i = 0; i < 4; ++i) {
            int fidx = (t + i * 256) * 4;
            int r = fidx >> 6;
            int k = fidx & 63;
            int gr = row0 + r;
            float4 v = make_float4(0.f, 0.f, 0.f, 0.f);
            if (gr < N) v = *(const float4*)(A + (size_t)gr * DIM + kt + k);
            *(float4*)(As + r * 68 + k) = v;
        }
        __syncthreads();

        const float* Ab = As + ty * 4 * 68;
        const float* Wb = Ws + (size_t)kt * 64 + tx * 4;
        #pragma unroll
        for (int k = 0; k < 64; k += 4) {
            float a[4][4];
            float w[4][4];
            #pragma unroll
            for (int i = 0; i < 4; ++i)
                *(float4*)a[i] = *(const float4*)(Ab + i * 68 + k);
            #pragma unroll
            for (int kk = 0; kk < 4; ++kk)
                *(float4*)w[kk] = *(const float4*)(Wb + (k + kk) * 64);
            #pragma unroll
            for (int kk = 0; kk < 4; ++kk)
                #pragma unroll
                for (int i = 0; i < 4; ++i)
                    #pragma unroll
                    for (int j = 0; j < 4; ++j)
                        acc[i][j] += a[i][kk] * w[kk][j];
        }
        __syncthreads();
    }

    float bb[4];
    #pragma unroll
    for (int j = 0; j < 4; ++j) bb[j] = bias[c0 + tx * 4 + j];
    #pragma unroll
    for (int i = 0; i < 4; ++i) {
        int gr = row0 + ty * 4 + i;
        if (gr < N) {
            float4 o;
            o.x = fmaxf(acc[i][0] + bb[0], 0.f);
            o.y = fmaxf(acc[i][1] + bb[1], 0.f);
            o.z = fmaxf(acc[i][2] + bb[2], 0.f);
            o.w = fmaxf(acc[i][3] + bb[3], 0.f);
            *(float4*)(out + (size_t)gr * DIM + c0 + tx * 4) = o;
        }
    }
}

static inline size_t align_up(size_t x, size_t a) { return (x + a - 1) & ~(a - 1); }

extern "C" void kernel_launch(void* const* d_in, const int* in_sizes, int n_in,
                              void* d_out, int out_size, void* d_ws, size_t ws_size,
                              hipStream_t stream) {
    const float* features = (const float*)d_in[0];
    const int*   src      = (const int*)d_in[1];
    const int*   dst      = (const int*)d_in[2];
    const float* W1       = (const float*)d_in[3];
    const float* b1       = (const float*)d_in[4];
    const float* W2       = (const float*)d_in[5];
    const float* b2       = (const float*)d_in[6];
    float* out = (float*)d_out;

    const int N = in_sizes[0] / DIM;
    const int E = in_sizes[1];
    const int B = (N + 255) / 256;        // scan blocks

    // workspace carve-up
    size_t nodeb = align_up((size_t)N * 4, 256);
    char* p = (char*)d_ws;
    int*   deg_out  = (int*)p;                      p += nodeb;
    int*   deg_in   = (int*)p;                      p += nodeb;
    int*   cursor   = (int*)p;                      p += nodeb;
    float* norm_src = (float*)p;                    p += nodeb;
    float* norm_dst = (float*)p;                    p += nodeb;
    int*   row_off  = (int*)p;                      p += align_up((size_t)(N + 1) * 4, 256);
    int*   bsum     = (int*)p;                      p += align_up((size_t)B * 4, 256);
    int*   bpre     = (int*)p;                      p += align_up((size_t)B * 4, 256);
    int*   csr_src  = (int*)p;                      p += align_up((size_t)E * 4, 256);
    float* agg      = (float*)p;                    p += (size_t)N * DIM * 4;
    float* h1       = (float*)p;                    p += (size_t)N * DIM * 4;

    const int edge_blocks = (E + 255) / 256;
    const int node_blocks = B;
    const int n4 = N * (DIM / 4);
    const int ps_blocks = (n4 + 255) / 256;
    const int spmm_blocks = (int)(((size_t)N * 32 + 255) / 256);
    dim3 gemm_grid((N + TM - 1) / TM, DIM / TN);

    // degrees + norms
    hipMemsetAsync(deg_out, 0, nodeb * 3, stream);  // deg_out, deg_in, cursor
    k_degrees<<<edge_blocks, 256, 0, stream>>>(src, dst, deg_out, deg_in, E);
    k_norms<<<node_blocks, 256, 0, stream>>>(deg_out, deg_in, norm_src, norm_dst, N);

    // CSR build (dst-sorted incoming edges)
    k_block_reduce<<<B, 256, 0, stream>>>(deg_in, bsum, N);
    k_scan_small<<<1, 256, 0, stream>>>(bsum, bpre, B);
    k_scan_final<<<B, 256, 0, stream>>>(deg_in, bpre, row_off, N);
    k_csr_fill<<<edge_blocks, 256, 0, stream>>>(src, dst, row_off, cursor, csr_src, E);

    // layer 1: hs = features*norm_src (into h1), spmm -> agg, gemm -> h1
    k_prescale<<<ps_blocks, 256, 0, stream>>>(features, norm_src, h1, n4);
    k_spmm<<<spmm_blocks, 256, 0, stream>>>(h1, csr_src, row_off, norm_dst, agg, N);
    k_gemm_bias_relu<<<gemm_grid, 256, 0, stream>>>(agg, W1, b1, h1, N);

    // layer 2: h1 *= norm_src (in place), spmm -> agg, gemm -> out
    k_prescale<<<ps_blocks, 256, 0, stream>>>(h1, norm_src, h1, n4);
    k_spmm<<<spmm_blocks, 256, 0, stream>>>(h1, csr_src, row_off, norm_dst, agg, N);
    k_gemm_bias_relu<<<gemm_grid, 256, 0, stream>>>(agg, W2, b2, out, N);
}

// Round 3
// 326.716 us; speedup vs baseline: 6.8156x; 1.0502x over previous
//
#include <hip/hip_runtime.h>

#define DIM 128   // feature dim, fixed per reference
#define GTM 32    // gemm tile rows
#define GTN 128   // gemm tile cols (= DIM, A read once)

// ---------------- degree histogram ----------------
__global__ __launch_bounds__(256) void k_degrees(const int* __restrict__ src,
                                                 const int* __restrict__ dst,
                                                 int* __restrict__ deg_out,
                                                 int* __restrict__ deg_in, int E) {
    int e = blockIdx.x * 256 + threadIdx.x;
    if (e < E) {
        atomicAdd(&deg_out[src[e]], 1);
        atomicAdd(&deg_in[dst[e]], 1);
    }
}

// ---------------- norms = clamp(deg,1)^-0.5 ----------------
__global__ __launch_bounds__(256) void k_norms(const int* __restrict__ deg_out,
                                               const int* __restrict__ deg_in,
                                               float* __restrict__ norm_src,
                                               float* __restrict__ norm_dst, int N) {
    int i = blockIdx.x * 256 + threadIdx.x;
    if (i < N) {
        int dov = deg_out[i]; if (dov < 1) dov = 1;
        int div_ = deg_in[i]; if (div_ < 1) div_ = 1;
        norm_src[i] = rsqrtf((float)dov);
        norm_dst[i] = rsqrtf((float)div_);
    }
}

// ---------------- scan step 1: per-block sums of deg_in ----------------
__global__ __launch_bounds__(256) void k_block_reduce(const int* __restrict__ deg,
                                                      int* __restrict__ bsum, int N) {
    __shared__ int wsum[4];
    int i = blockIdx.x * 256 + threadIdx.x;
    int x = (i < N) ? deg[i] : 0;
    #pragma unroll
    for (int off = 32; off > 0; off >>= 1) x += __shfl_down(x, off, 64);
    int lane = threadIdx.x & 63, wave = threadIdx.x >> 6;
    if (lane == 0) wsum[wave] = x;
    __syncthreads();
    if (threadIdx.x == 0) bsum[blockIdx.x] = wsum[0] + wsum[1] + wsum[2] + wsum[3];
}

// ---------------- scan step 2: exclusive scan of block sums (1 block) ----------------
__global__ __launch_bounds__(256) void k_scan_small(const int* __restrict__ bsum,
                                                    int* __restrict__ bpre, int B) {
    __shared__ int wsum[4];
    __shared__ int carry_s;
    if (threadIdx.x == 0) carry_s = 0;
    __syncthreads();
    int lane = threadIdx.x & 63, wave = threadIdx.x >> 6;
    for (int base = 0; base < B; base += 256) {
        int i = base + threadIdx.x;
        int x = (i < B) ? bsum[i] : 0;
        int orig = x;
        #pragma unroll
        for (int off = 1; off < 64; off <<= 1) {
            int y = __shfl_up(x, off, 64);
            if (lane >= off) x += y;
        }
        if (lane == 63) wsum[wave] = x;
        __syncthreads();
        if (threadIdx.x == 0) {
            int s = 0;
            for (int w = 0; w < 4; ++w) { int t = wsum[w]; wsum[w] = s; s += t; }
        }
        __syncthreads();
        x += wsum[wave] + carry_s;
        if (i < B) bpre[i] = x - orig;
        __syncthreads();
        if (threadIdx.x == 255) carry_s = x;
        __syncthreads();
    }
}

// ---------------- scan step 3: block-local scan + offset -> row_off ----------------
__global__ __launch_bounds__(256) void k_scan_final(const int* __restrict__ deg,
                                                    const int* __restrict__ bpre,
                                                    int* __restrict__ row_off, int N) {
    __shared__ int wsum[4];
    int i = blockIdx.x * 256 + threadIdx.x;
    int x = (i < N) ? deg[i] : 0;
    int orig = x;
    int lane = threadIdx.x & 63, wave = threadIdx.x >> 6;
    #pragma unroll
    for (int off = 1; off < 64; off <<= 1) {
        int y = __shfl_up(x, off, 64);
        if (lane >= off) x += y;
    }
    if (lane == 63) wsum[wave] = x;
    __syncthreads();
    if (threadIdx.x == 0) {
        int s = 0;
        for (int w = 0; w < 4; ++w) { int t = wsum[w]; wsum[w] = s; s += t; }
    }
    __syncthreads();
    x += wsum[wave] + bpre[blockIdx.x];
    if (i < N) row_off[i] = x - orig;
    if (i == N - 1) row_off[N] = x;
}

// ---------------- CSR fill: scatter src ids under dst buckets ----------------
__global__ __launch_bounds__(256) void k_csr_fill(const int* __restrict__ src,
                                                  const int* __restrict__ dst,
                                                  const int* __restrict__ row_off,
                                                  int* __restrict__ cursor,
                                                  int* __restrict__ csr_src, int E) {
    int e = blockIdx.x * 256 + threadIdx.x;
    if (e < E) {
        int d = dst[e];
        int pos = row_off[d] + atomicAdd(&cursor[d], 1);
        csr_src[pos] = src[e];
    }
}

// ---------------- CSR SpMM: agg[d] = nd[d] * sum_s ns[s]*h[s] ----------------
// 32 lanes per node, float4 per lane; norm_src folded into the gather FMA;
// 4-deep edge unroll for memory-level parallelism on the random gathers.
__global__ __launch_bounds__(256) void k_spmm(const float* __restrict__ h,
                                              const int* __restrict__ csr_src,
                                              const int* __restrict__ row_off,
                                              const float* __restrict__ norm_src,
                                              const float* __restrict__ norm_dst,
                                              float* __restrict__ agg, int N) {
    int t = blockIdx.x * 256 + threadIdx.x;
    int node = t >> 5;
    int lane = t & 31;
    if (node >= N) return;
    int beg = row_off[node], end = row_off[node + 1];
    float4 acc = make_float4(0.f, 0.f, 0.f, 0.f);
    int i = beg;
    for (; i + 4 <= end; i += 4) {
        int s0 = csr_src[i];
        int s1 = csr_src[i + 1];
        int s2 = csr_src[i + 2];
        int s3 = csr_src[i + 3];
        float n0 = norm_src[s0], n1 = norm_src[s1], n2 = norm_src[s2], n3 = norm_src[s3];
        float4 v0 = *((const float4*)(h + (size_t)s0 * DIM) + lane);
        float4 v1 = *((const float4*)(h + (size_t)s1 * DIM) + lane);
        float4 v2 = *((const float4*)(h + (size_t)s2 * DIM) + lane);
        float4 v3 = *((const float4*)(h + (size_t)s3 * DIM) + lane);
        acc.x += v0.x * n0; acc.y += v0.y * n0; acc.z += v0.z * n0; acc.w += v0.w * n0;
        acc.x += v1.x * n1; acc.y += v1.y * n1; acc.z += v1.z * n1; acc.w += v1.w * n1;
        acc.x += v2.x * n2; acc.y += v2.y * n2; acc.z += v2.z * n2; acc.w += v2.w * n2;
        acc.x += v3.x * n3; acc.y += v3.y * n3; acc.z += v3.z * n3; acc.w += v3.w * n3;
    }
    for (; i < end; ++i) {
        int s0 = csr_src[i];
        float n0 = norm_src[s0];
        float4 v0 = *((const float4*)(h + (size_t)s0 * DIM) + lane);
        acc.x += v0.x * n0; acc.y += v0.y * n0; acc.z += v0.z * n0; acc.w += v0.w * n0;
    }
    float nd = norm_dst[node];
    acc.x *= nd; acc.y *= nd; acc.z *= nd; acc.w *= nd;
    *((float4*)(agg + (size_t)node * DIM) + lane) = acc;
}

// ---------------- fused: out = relu(agg @ W + b) ----------------
// 32x128 tile, 256 threads, 4x4 acc/thread. Full W (64 KB) staged once,
// A in 64-k chunks (stride 68). 72.7 KB LDS -> 2 blocks/CU.
__global__ __launch_bounds__(256, 2) void k_gemm_bias_relu(
        const float* __restrict__ A, const float* __restrict__ W,
        const float* __restrict__ bias, float* __restrict__ out, int N) {
    __shared__ float Ws[DIM * GTN];   // [k][c] 64 KB
    __shared__ float As[GTM * 68];    // [r][64-k chunk], stride 68

    const int t = threadIdx.x;
    const int row0 = blockIdx.x * GTM;

    // stage all of W: 16384 floats = 16 float4/thread, coalesced copy
    #pragma unroll
    for (int i = 0; i < 16; ++i) {
        int idx = (t + i * 256) * 4;
        *(float4*)(Ws + idx) = *(const float4*)(W + idx);
    }

    const int tx = t & 31;    // col group -> cols tx*4..+3
    const int ty = t >> 5;    // row group -> rows ty*4..+3
    const int c0t = tx * 4;

    float acc[4][4];
    #pragma unroll
    for (int i = 0; i < 4; ++i)
        #pragma unroll
        for (int j = 0; j < 4; ++j) acc[i][j] = 0.f;

    for (int kt = 0; kt < DIM; kt += 64) {
        // stage A chunk: 32x64 floats = 2 float4/thread
        #pragma unroll
        for (int i = 0; i < 2; ++i) {
            int fidx = (t + i * 256) * 4;
            int r = fidx >> 6;
            int k = fidx & 63;
            int gr = row0 + r;
            float4 v = make_float4(0.f, 0.f, 0.f, 0.f);
            if (gr < N) v = *(const float4*)(A + (size_t)gr * DIM + kt + k);
            *(float4*)(As + r * 68 + k) = v;
        }
        __syncthreads();

        #pragma unroll 4
        for (int k = 0; k < 64; k += 4) {
            float a[4][4];   // [row][kk]
            float w[4][4];   // [kk][col]
            #pragma unroll
            for (int i = 0; i < 4; ++i)
                *(float4*)a[i] = *(const float4*)(As + (ty * 4 + i) * 68 + k);
            #pragma unroll
            for (int kk = 0; kk < 4; ++kk)
                *(float4*)w[kk] = *(const float4*)(Ws + (kt + k + kk) * GTN + c0t);
            #pragma unroll
            for (int kk = 0; kk < 4; ++kk)
                #pragma unroll
                for (int i = 0; i < 4; ++i)
                    #pragma unroll
                    for (int j = 0; j < 4; ++j)
                        acc[i][j] += a[i][kk] * w[kk][j];
        }
        __syncthreads();
    }

    float bb[4];
    #pragma unroll
    for (int j = 0; j < 4; ++j) bb[j] = bias[c0t + j];
    #pragma unroll
    for (int i = 0; i < 4; ++i) {
        int gr = row0 + ty * 4 + i;
        if (gr < N) {
            float4 o;
            o.x = fmaxf(acc[i][0] + bb[0], 0.f);
            o.y = fmaxf(acc[i][1] + bb[1], 0.f);
            o.z = fmaxf(acc[i][2] + bb[2], 0.f);
            o.w = fmaxf(acc[i][3] + bb[3], 0.f);
            *(float4*)(out + (size_t)gr * DIM + c0t) = o;
        }
    }
}

static inline size_t align_up(size_t x, size_t a) { return (x + a - 1) & ~(a - 1); }

extern "C" void kernel_launch(void* const* d_in, const int* in_sizes, int n_in,
                              void* d_out, int out_size, void* d_ws, size_t ws_size,
                              hipStream_t stream) {
    const float* features = (const float*)d_in[0];
    const int*   src      = (const int*)d_in[1];
    const int*   dst      = (const int*)d_in[2];
    const float* W1       = (const float*)d_in[3];
    const float* b1       = (const float*)d_in[4];
    const float* W2       = (const float*)d_in[5];
    const float* b2       = (const float*)d_in[6];
    float* out = (float*)d_out;

    const int N = in_sizes[0] / DIM;
    const int E = in_sizes[1];
    const int B = (N + 255) / 256;

    // workspace carve-up
    size_t nodeb = align_up((size_t)N * 4, 256);
    char* p = (char*)d_ws;
    int*   deg_out  = (int*)p;                      p += nodeb;
    int*   deg_in   = (int*)p;                      p += nodeb;
    int*   cursor   = (int*)p;                      p += nodeb;
    float* norm_src = (float*)p;                    p += nodeb;
    float* norm_dst = (float*)p;                    p += nodeb;
    int*   row_off  = (int*)p;                      p += align_up((size_t)(N + 1) * 4, 256);
    int*   bsum     = (int*)p;                      p += align_up((size_t)B * 4, 256);
    int*   bpre     = (int*)p;                      p += align_up((size_t)B * 4, 256);
    int*   csr_src  = (int*)p;                      p += align_up((size_t)E * 4, 256);
    float* agg      = (float*)p;                    p += (size_t)N * DIM * 4;
    float* h1       = (float*)p;                    p += (size_t)N * DIM * 4;

    const int edge_blocks = (E + 255) / 256;
    const int node_blocks = B;
    const int spmm_blocks = (int)(((size_t)N * 32 + 255) / 256);
    const int gemm_blocks = (N + GTM - 1) / GTM;

    // degrees + norms
    hipMemsetAsync(deg_out, 0, nodeb * 3, stream);  // deg_out, deg_in, cursor
    k_degrees<<<edge_blocks, 256, 0, stream>>>(src, dst, deg_out, deg_in, E);
    k_norms<<<node_blocks, 256, 0, stream>>>(deg_out, deg_in, norm_src, norm_dst, N);

    // CSR build (dst-sorted incoming edges)
    k_block_reduce<<<B, 256, 0, stream>>>(deg_in, bsum, N);
    k_scan_small<<<1, 256, 0, stream>>>(bsum, bpre, B);
    k_scan_final<<<B, 256, 0, stream>>>(deg_in, bpre, row_off, N);
    k_csr_fill<<<edge_blocks, 256, 0, stream>>>(src, dst, row_off, cursor, csr_src, E);

    // layer 1
    k_spmm<<<spmm_blocks, 256, 0, stream>>>(features, csr_src, row_off, norm_src, norm_dst, agg, N);
    k_gemm_bias_relu<<<gemm_blocks, 256, 0, stream>>>(agg, W1, b1, h1, N);

    // layer 2
    k_spmm<<<spmm_blocks, 256, 0, stream>>>(h1, csr_src, row_off, norm_src, norm_dst, agg, N);
    k_gemm_bias_relu<<<gemm_blocks, 256, 0, stream>>>(agg, W2, b2, out, N);
}

// Round 4
// 306.402 us; speedup vs baseline: 7.2675x; 1.0663x over previous
//
#include <hip/hip_runtime.h>

#define DIM 128   // feature dim, fixed per reference
#define GTM 32    // gemm tile rows
#define GTN 128   // gemm tile cols (= DIM, A read once)

// ---------------- edge pass: deg_out histogram + deg_in histogram w/ slot capture ----------------
// local[e] = this edge's rank among edges sharing its dst -> atomic-free CSR fill later.
__global__ __launch_bounds__(256) void k_edge_pass(const int* __restrict__ src,
                                                   const int* __restrict__ dst,
                                                   int* __restrict__ deg_out,
                                                   int* __restrict__ cnt,
                                                   int* __restrict__ local, int E) {
    int e = blockIdx.x * 256 + threadIdx.x;
    if (e < E) {
        atomicAdd(&deg_out[src[e]], 1);
        local[e] = atomicAdd(&cnt[dst[e]], 1);
    }
}

// ---------------- scan step 1: per-block sums of cnt ----------------
__global__ __launch_bounds__(256) void k_block_reduce(const int* __restrict__ deg,
                                                      int* __restrict__ bsum, int N) {
    __shared__ int wsum[4];
    int i = blockIdx.x * 256 + threadIdx.x;
    int x = (i < N) ? deg[i] : 0;
    #pragma unroll
    for (int off = 32; off > 0; off >>= 1) x += __shfl_down(x, off, 64);
    int lane = threadIdx.x & 63, wave = threadIdx.x >> 6;
    if (lane == 0) wsum[wave] = x;
    __syncthreads();
    if (threadIdx.x == 0) bsum[blockIdx.x] = wsum[0] + wsum[1] + wsum[2] + wsum[3];
}

// ---------------- scan step 2: exclusive scan of block sums (1 block) ----------------
__global__ __launch_bounds__(256) void k_scan_small(const int* __restrict__ bsum,
                                                    int* __restrict__ bpre, int B) {
    __shared__ int wsum[4];
    __shared__ int carry_s;
    if (threadIdx.x == 0) carry_s = 0;
    __syncthreads();
    int lane = threadIdx.x & 63, wave = threadIdx.x >> 6;
    for (int base = 0; base < B; base += 256) {
        int i = base + threadIdx.x;
        int x = (i < B) ? bsum[i] : 0;
        int orig = x;
        #pragma unroll
        for (int off = 1; off < 64; off <<= 1) {
            int y = __shfl_up(x, off, 64);
            if (lane >= off) x += y;
        }
        if (lane == 63) wsum[wave] = x;
        __syncthreads();
        if (threadIdx.x == 0) {
            int s = 0;
            for (int w = 0; w < 4; ++w) { int t = wsum[w]; wsum[w] = s; s += t; }
        }
        __syncthreads();
        x += wsum[wave] + carry_s;
        if (i < B) bpre[i] = x - orig;
        __syncthreads();
        if (threadIdx.x == 255) carry_s = x;
        __syncthreads();
    }
}

// ---------------- scan step 3: row_off + both norms (fused) ----------------
__global__ __launch_bounds__(256) void k_scan_final(const int* __restrict__ cnt,
                                                    const int* __restrict__ deg_out,
                                                    const int* __restrict__ bpre,
                                                    int* __restrict__ row_off,
                                                    float* __restrict__ norm_src,
                                                    float* __restrict__ norm_dst, int N) {
    __shared__ int wsum[4];
    int i = blockIdx.x * 256 + threadIdx.x;
    int x = (i < N) ? cnt[i] : 0;
    int orig = x;
    int lane = threadIdx.x & 63, wave = threadIdx.x >> 6;
    #pragma unroll
    for (int off = 1; off < 64; off <<= 1) {
        int y = __shfl_up(x, off, 64);
        if (lane >= off) x += y;
    }
    if (lane == 63) wsum[wave] = x;
    __syncthreads();
    if (threadIdx.x == 0) {
        int s = 0;
        for (int w = 0; w < 4; ++w) { int t = wsum[w]; wsum[w] = s; s += t; }
    }
    __syncthreads();
    x += wsum[wave] + bpre[blockIdx.x];
    if (i < N) {
        row_off[i] = x - orig;                    // exclusive prefix
        int di = orig < 1 ? 1 : orig;             // deg_in clamp
        norm_dst[i] = rsqrtf((float)di);
        int dov = deg_out[i]; if (dov < 1) dov = 1;
        norm_src[i] = rsqrtf((float)dov);
    }
    if (i == N - 1) row_off[N] = x;               // total
}

// ---------------- CSR fill: pure scatter, no atomics ----------------
__global__ __launch_bounds__(256) void k_fill(const int* __restrict__ src,
                                              const int* __restrict__ dst,
                                              const int* __restrict__ row_off,
                                              const int* __restrict__ local,
                                              int* __restrict__ csr_src, int E) {
    int e = blockIdx.x * 256 + threadIdx.x;
    if (e < E) {
        int pos = row_off[dst[e]] + local[e];
        csr_src[pos] = src[e];
    }
}

// ---------------- CSR SpMM: agg[d] = nd[d] * sum_s ns[s]*h[s] ----------------
// 32 lanes per node, float4 per lane; 4-deep edge unroll for MLP on gathers.
__global__ __launch_bounds__(256) void k_spmm(const float* __restrict__ h,
                                              const int* __restrict__ csr_src,
                                              const int* __restrict__ row_off,
                                              const float* __restrict__ norm_src,
                                              const float* __restrict__ norm_dst,
                                              float* __restrict__ agg, int N) {
    int t = blockIdx.x * 256 + threadIdx.x;
    int node = t >> 5;
    int lane = t & 31;
    if (node >= N) return;
    int beg = row_off[node], end = row_off[node + 1];
    float4 acc = make_float4(0.f, 0.f, 0.f, 0.f);
    int i = beg;
    for (; i + 4 <= end; i += 4) {
        int s0 = csr_src[i];
        int s1 = csr_src[i + 1];
        int s2 = csr_src[i + 2];
        int s3 = csr_src[i + 3];
        float n0 = norm_src[s0], n1 = norm_src[s1], n2 = norm_src[s2], n3 = norm_src[s3];
        float4 v0 = *((const float4*)(h + (size_t)s0 * DIM) + lane);
        float4 v1 = *((const float4*)(h + (size_t)s1 * DIM) + lane);
        float4 v2 = *((const float4*)(h + (size_t)s2 * DIM) + lane);
        float4 v3 = *((const float4*)(h + (size_t)s3 * DIM) + lane);
        acc.x += v0.x * n0; acc.y += v0.y * n0; acc.z += v0.z * n0; acc.w += v0.w * n0;
        acc.x += v1.x * n1; acc.y += v1.y * n1; acc.z += v1.z * n1; acc.w += v1.w * n1;
        acc.x += v2.x * n2; acc.y += v2.y * n2; acc.z += v2.z * n2; acc.w += v2.w * n2;
        acc.x += v3.x * n3; acc.y += v3.y * n3; acc.z += v3.z * n3; acc.w += v3.w * n3;
    }
    for (; i < end; ++i) {
        int s0 = csr_src[i];
        float n0 = norm_src[s0];
        float4 v0 = *((const float4*)(h + (size_t)s0 * DIM) + lane);
        acc.x += v0.x * n0; acc.y += v0.y * n0; acc.z += v0.z * n0; acc.w += v0.w * n0;
    }
    float nd = norm_dst[node];
    acc.x *= nd; acc.y *= nd; acc.z *= nd; acc.w *= nd;
    *((float4*)(agg + (size_t)node * DIM) + lane) = acc;
}

// ---------------- fused: out = relu(agg @ W + b) ----------------
// 32x128 tile, 256 threads, 4x4 acc/thread. Full W (64 KB) staged once,
// A in 64-k chunks (stride 68). 72.7 KB LDS -> 2 blocks/CU.
__global__ __launch_bounds__(256, 2) void k_gemm_bias_relu(
        const float* __restrict__ A, const float* __restrict__ W,
        const float* __restrict__ bias, float* __restrict__ out, int N) {
    __shared__ float Ws[DIM * GTN];   // [k][c] 64 KB
    __shared__ float As[GTM * 68];    // [r][64-k chunk], stride 68

    const int t = threadIdx.x;
    const int row0 = blockIdx.x * GTM;

    #pragma unroll
    for (int i = 0; i < 16; ++i) {
        int idx = (t + i * 256) * 4;
        *(float4*)(Ws + idx) = *(const float4*)(W + idx);
    }

    const int tx = t & 31;    // col group -> cols tx*4..+3
    const int ty = t >> 5;    // row group -> rows ty*4..+3
    const int c0t = tx * 4;

    float acc[4][4];
    #pragma unroll
    for (int i = 0; i < 4; ++i)
        #pragma unroll
        for (int j = 0; j < 4; ++j) acc[i][j] = 0.f;

    for (int kt = 0; kt < DIM; kt += 64) {
        #pragma unroll
        for (int i = 0; i < 2; ++i) {
            int fidx = (t + i * 256) * 4;
            int r = fidx >> 6;
            int k = fidx & 63;
            int gr = row0 + r;
            float4 v = make_float4(0.f, 0.f, 0.f, 0.f);
            if (gr < N) v = *(const float4*)(A + (size_t)gr * DIM + kt + k);
            *(float4*)(As + r * 68 + k) = v;
        }
        __syncthreads();

        #pragma unroll 4
        for (int k = 0; k < 64; k += 4) {
            float a[4][4];
            float w[4][4];
            #pragma unroll
            for (int i = 0; i < 4; ++i)
                *(float4*)a[i] = *(const float4*)(As + (ty * 4 + i) * 68 + k);
            #pragma unroll
            for (int kk = 0; kk < 4; ++kk)
                *(float4*)w[kk] = *(const float4*)(Ws + (kt + k + kk) * GTN + c0t);
            #pragma unroll
            for (int kk = 0; kk < 4; ++kk)
                #pragma unroll
                for (int i = 0; i < 4; ++i)
                    #pragma unroll
                    for (int j = 0; j < 4; ++j)
                        acc[i][j] += a[i][kk] * w[kk][j];
        }
        __syncthreads();
    }

    float bb[4];
    #pragma unroll
    for (int j = 0; j < 4; ++j) bb[j] = bias[c0t + j];
    #pragma unroll
    for (int i = 0; i < 4; ++i) {
        int gr = row0 + ty * 4 + i;
        if (gr < N) {
            float4 o;
            o.x = fmaxf(acc[i][0] + bb[0], 0.f);
            o.y = fmaxf(acc[i][1] + bb[1], 0.f);
            o.z = fmaxf(acc[i][2] + bb[2], 0.f);
            o.w = fmaxf(acc[i][3] + bb[3], 0.f);
            *(float4*)(out + (size_t)gr * DIM + c0t) = o;
        }
    }
}

static inline size_t align_up(size_t x, size_t a) { return (x + a - 1) & ~(a - 1); }

extern "C" void kernel_launch(void* const* d_in, const int* in_sizes, int n_in,
                              void* d_out, int out_size, void* d_ws, size_t ws_size,
                              hipStream_t stream) {
    const float* features = (const float*)d_in[0];
    const int*   src      = (const int*)d_in[1];
    const int*   dst      = (const int*)d_in[2];
    const float* W1       = (const float*)d_in[3];
    const float* b1       = (const float*)d_in[4];
    const float* W2       = (const float*)d_in[5];
    const float* b2       = (const float*)d_in[6];
    float* out = (float*)d_out;

    const int N = in_sizes[0] / DIM;
    const int E = in_sizes[1];
    const int B = (N + 255) / 256;

    // workspace carve-up
    size_t nodeb = align_up((size_t)N * 4, 256);
    char* p = (char*)d_ws;
    int*   deg_out  = (int*)p;                      p += nodeb;
    int*   cnt      = (int*)p;                      p += nodeb;
    float* norm_src = (float*)p;                    p += nodeb;
    float* norm_dst = (float*)p;                    p += nodeb;
    int*   row_off  = (int*)p;                      p += align_up((size_t)(N + 1) * 4, 256);
    int*   bsum     = (int*)p;                      p += align_up((size_t)B * 4, 256);
    int*   bpre     = (int*)p;                      p += align_up((size_t)B * 4, 256);
    int*   csr_src  = (int*)p;                      p += align_up((size_t)E * 4, 256);
    float* agg      = (float*)p;                    p += (size_t)N * DIM * 4;
    float* h1       = (float*)p;                    p += (size_t)N * DIM * 4;
    // local[E] aliases agg: dead after k_fill, agg first written by k_spmm later
    int*   local    = (int*)agg;

    const int edge_blocks = (E + 255) / 256;
    const int spmm_blocks = (int)(((size_t)N * 32 + 255) / 256);
    const int gemm_blocks = (N + GTM - 1) / GTM;

    // graph build: 1.2M atomics total (the floor for two histograms)
    hipMemsetAsync(deg_out, 0, nodeb * 2, stream);  // deg_out, cnt
    k_edge_pass<<<edge_blocks, 256, 0, stream>>>(src, dst, deg_out, cnt, local, E);
    k_block_reduce<<<B, 256, 0, stream>>>(cnt, bsum, N);
    k_scan_small<<<1, 256, 0, stream>>>(bsum, bpre, B);
    k_scan_final<<<B, 256, 0, stream>>>(cnt, deg_out, bpre, row_off, norm_src, norm_dst, N);
    k_fill<<<edge_blocks, 256, 0, stream>>>(src, dst, row_off, local, csr_src, E);

    // layer 1
    k_spmm<<<spmm_blocks, 256, 0, stream>>>(features, csr_src, row_off, norm_src, norm_dst, agg, N);
    k_gemm_bias_relu<<<gemm_blocks, 256, 0, stream>>>(agg, W1, b1, h1, N);

    // layer 2
    k_spmm<<<spmm_blocks, 256, 0, stream>>>(h1, csr_src, row_off, norm_src, norm_dst, agg, N);
    k_gemm_bias_relu<<<gemm_blocks, 256, 0, stream>>>(agg, W2, b2, out, N);
}